// Round 11
// baseline (289.588 us; speedup 1.0000x reference)
//
#include <hip/hip_runtime.h>
#include <hip/hip_bf16.h>

// Problem constants
#define BB 4
#define HH 64
#define WW 64
#define LL 4096           // HH*WW
#define DM 192            // D_MODEL
#define DI 384            // D_INNER
#define NS 16             // D_STATE
#define RK 12             // DT_RANK
#define NC 256            // number of scan chunks
#define CH 16             // chunk length (NC*CH == LL)
#define ROWS 16384        // BB*LL
#define XDS 64            // xdbl row stride (44 cols meaningful)
#define KA 576            // fused A' width: 384 u_bf | 192 prompt_bf
#define LOG2E 1.44269504f
#define LN2   0.69314718f

typedef __bf16 bf16x8 __attribute__((ext_vector_type(8)));
typedef float  f32x4  __attribute__((ext_vector_type(4)));

#if defined(__has_builtin)
#if __has_builtin(__builtin_amdgcn_exp2f)
#define fexp2(x) __builtin_amdgcn_exp2f(x)
#else
#define fexp2(x) exp2f(x)
#endif
#else
#define fexp2(x) exp2f(x)
#endif

__device__ __forceinline__ float fsilu(float x) {
    return x / (1.0f + __expf(-x));
}

// f32 -> bf16 (RNE)
__device__ __forceinline__ unsigned short f2bf(float f) {
    unsigned int u = __float_as_uint(f);
    unsigned int r = (u + 0x7fffu + ((u >> 16) & 1u)) >> 16;
    return (unsigned short)r;
}
// bf16 -> f32
__device__ __forceinline__ float bf2f(unsigned short v) {
    return __uint_as_float((unsigned int)v << 16);
}

// ---------------------------------------------------------------------------
// x (ROWS x DM f32) -> x_bf (bf16, contiguous)
// ---------------------------------------------------------------------------
__global__ __launch_bounds__(256) void f32_to_bf16_vec(
    const float* __restrict__ src, unsigned short* __restrict__ dst, int n4)
{
    int i = blockIdx.x * 256 + threadIdx.x;
    if (i < n4) {
        float4 v = ((const float4*)src)[i];
        ((ushort4*)dst)[i] = make_ushort4(f2bf(v.x), f2bf(v.y), f2bf(v.z), f2bf(v.w));
    }
}

// ---------------------------------------------------------------------------
// prompt (ROWS x DM f32) -> Across cols 384..575 (stride KA, bf16)
// ---------------------------------------------------------------------------
__global__ __launch_bounds__(256) void prompt_to_across(
    const float* __restrict__ prompt, unsigned short* __restrict__ Across)
{
    int i4 = blockIdx.x * 256 + threadIdx.x;     // ROWS * 48
    if (i4 >= ROWS * (DM / 4)) return;
    int row = i4 / (DM / 4), c4 = i4 % (DM / 4);
    float4 v = ((const float4*)prompt)[i4];
    *(ushort4*)&Across[(size_t)row * KA + DI + c4 * 4] =
        make_ushort4(f2bf(v.x), f2bf(v.y), f2bf(v.z), f2bf(v.w));
}

// ---------------------------------------------------------------------------
// Build transposed bf16 weight: src (K x Nsrc f32) -> dst (Nrows x K bf16)
// ---------------------------------------------------------------------------
__global__ __launch_bounds__(256) void build_bt(
    const float* __restrict__ src, unsigned short* __restrict__ dst,
    int K, int Nsrc, int Nrows)
{
    int idx = blockIdx.x * 256 + threadIdx.x;
    if (idx >= Nrows * K) return;
    int n = idx / K, k = idx % K;
    dst[idx] = (n < Nsrc) ? f2bf(src[k * Nsrc + n]) : (unsigned short)0;
}

// ---------------------------------------------------------------------------
// Build fused B' (XDS rows x KA cols, transposed N x K)
// ---------------------------------------------------------------------------
__global__ __launch_bounds__(256) void build_bxt(
    const float* __restrict__ Wx, const float* __restrict__ Wp,
    unsigned short* __restrict__ dst)
{
    int idx = blockIdx.x * 256 + threadIdx.x;    // XDS * KA
    if (idx >= XDS * KA) return;
    int n = idx / KA, k = idx % KA;
    float v = 0.f;
    if (k < DI) { if (n < 44) v = Wx[k * 44 + n]; }
    else        { if (n >= 28 && n < 44) v = Wp[(k - DI) * NS + (n - 28)]; }
    dst[idx] = f2bf(v);
}

// ---------------------------------------------------------------------------
// bf16 MFMA GEMM: C = A(MxK bf16) * BT^T (BT is N x K bf16).  64x64 tile,
// BK=32, 4 waves x (2x2) 16x16x32 fragments, LDS stride 80B.
// SPLIT: cols < halfN -> C0 (f32, stride halfN); cols >= halfN -> C1z (bf16).
// ---------------------------------------------------------------------------
template<bool SPLIT>
__global__ __launch_bounds__(256) void gemm_bf16_mfma(
    const unsigned short* __restrict__ A, const unsigned short* __restrict__ BT,
    float* __restrict__ C0, unsigned short* __restrict__ C1z,
    int M, int N, int K, int halfN)
{
    __shared__ __align__(16) char lds[64 * 80 * 2];
    char* As = lds;
    char* Bs = lds + 64 * 80;
    const int tid = threadIdx.x;
    const int w = tid >> 6, lane = tid & 63;
    const int wm = w >> 1, wn = w & 1;
    const int row0 = blockIdx.x * 64, col0 = blockIdx.y * 64;
    const int r = tid >> 2, cch = tid & 3;
    const int l15 = lane & 15, k8 = lane >> 4;

    f32x4 acc[2][2] = {};
    for (int k0 = 0; k0 < K; k0 += 32) {
        *(float4*)(As + r * 80 + cch * 16) =
            *(const float4*)(A + (size_t)(row0 + r) * K + k0 + cch * 8);
        *(float4*)(Bs + r * 80 + cch * 16) =
            *(const float4*)(BT + (size_t)(col0 + r) * K + k0 + cch * 8);
        __syncthreads();
        bf16x8 a0 = *(const bf16x8*)(As + (wm * 32 +      l15) * 80 + k8 * 16);
        bf16x8 a1 = *(const bf16x8*)(As + (wm * 32 + 16 + l15) * 80 + k8 * 16);
        bf16x8 b0 = *(const bf16x8*)(Bs + (wn * 32 +      l15) * 80 + k8 * 16);
        bf16x8 b1 = *(const bf16x8*)(Bs + (wn * 32 + 16 + l15) * 80 + k8 * 16);
        acc[0][0] = __builtin_amdgcn_mfma_f32_16x16x32_bf16(a0, b0, acc[0][0], 0, 0, 0);
        acc[0][1] = __builtin_amdgcn_mfma_f32_16x16x32_bf16(a0, b1, acc[0][1], 0, 0, 0);
        acc[1][0] = __builtin_amdgcn_mfma_f32_16x16x32_bf16(a1, b0, acc[1][0], 0, 0, 0);
        acc[1][1] = __builtin_amdgcn_mfma_f32_16x16x32_bf16(a1, b1, acc[1][1], 0, 0, 0);
        __syncthreads();
    }

    if (SPLIT && col0 >= halfN) {
        const int cbase = col0 - halfN;
        #pragma unroll
        for (int fm = 0; fm < 2; ++fm)
            #pragma unroll
            for (int fn = 0; fn < 2; ++fn)
                #pragma unroll
                for (int reg = 0; reg < 4; ++reg) {
                    int row = row0 + wm * 32 + fm * 16 + k8 * 4 + reg;
                    int col = cbase + wn * 32 + fn * 16 + l15;
                    C1z[(size_t)row * halfN + col] = f2bf(acc[fm][fn][reg]);
                }
    } else {
        const int cstride = SPLIT ? halfN : N;
        #pragma unroll
        for (int fm = 0; fm < 2; ++fm)
            #pragma unroll
            for (int fn = 0; fn < 2; ++fn)
                #pragma unroll
                for (int reg = 0; reg < 4; ++reg) {
                    int row = row0 + wm * 32 + fm * 16 + k8 * 4 + reg;
                    int col = col0 + wn * 32 + fn * 16 + l15;
                    C0[(size_t)row * cstride + col] = acc[fm][fn][reg];
                }
    }
}

// ---------------------------------------------------------------------------
// Depthwise 3x3 conv (channel-last), bias + SiLU.
// xi (B,H,W,DI f32) -> u_bf (bf16) written into Across cols 0..383 (stride KA)
// ---------------------------------------------------------------------------
__global__ __launch_bounds__(256) void conv_dw_silu(
    const float* __restrict__ xi, const float* __restrict__ conv_w,
    const float* __restrict__ conv_b, unsigned short* __restrict__ Across)
{
    int idx = blockIdx.x * 256 + threadIdx.x;   // total BB*HH*WW*96
    int c4 = idx % 96;
    int rest = idx / 96;
    int w = rest % WW; rest /= WW;
    int h = rest % HH;
    int b = rest / HH;
    int c = c4 * 4;

    float wgt[4][9];
    #pragma unroll
    for (int q = 0; q < 4; ++q)
        #pragma unroll
        for (int t = 0; t < 9; ++t)
            wgt[q][t] = conv_w[(c + q) * 9 + t];

    float4 acc = *(const float4*)&conv_b[c];
    #pragma unroll
    for (int kh = 0; kh < 3; ++kh) {
        int hh = h + kh - 1;
        if ((unsigned)hh >= HH) continue;
        #pragma unroll
        for (int kw = 0; kw < 3; ++kw) {
            int ww = w + kw - 1;
            if ((unsigned)ww >= WW) continue;
            const float4 xv = *(const float4*)&xi[(((size_t)(b * HH + hh)) * WW + ww) * DI + c];
            int t = kh * 3 + kw;
            acc.x += xv.x * wgt[0][t];
            acc.y += xv.y * wgt[1][t];
            acc.z += xv.z * wgt[2][t];
            acc.w += xv.w * wgt[3][t];
        }
    }
    acc.x = fsilu(acc.x); acc.y = fsilu(acc.y);
    acc.z = fsilu(acc.z); acc.w = fsilu(acc.w);
    size_t off = (((size_t)b * LL) + h * WW + w) * KA + c;
    *(ushort4*)&Across[off] = make_ushort4(f2bf(acc.x), f2bf(acc.y), f2bf(acc.z), f2bf(acc.w));
}

// ---------------------------------------------------------------------------
// Scan phase 1 v6: one block = one (b,chunk), 384 threads (thread = d).
// xdbl chunk rows staged in LDS once; u preloaded to registers; main loop has
// zero global loads.  Writes interleaved AH pairs {ap, h}.
// ---------------------------------------------------------------------------
__global__ __launch_bounds__(384) void scan_p1_v6(
    const unsigned short* __restrict__ uA, const float* __restrict__ xdbl,
    const float* __restrict__ A_log, const float* __restrict__ Wdt,
    const float* __restrict__ b_dt, float* __restrict__ AH)
{
    __shared__ __align__(16) float xlds[CH * XDS];   // 4 KB
    const int d = threadIdx.x;
    const int bc = blockIdx.x;                        // b*NC + c
    const int b = bc / NC, c = bc % NC;
    const size_t rbase = (size_t)(b * LL + c * CH);

    // stage xdbl chunk (16 rows x 64 f32, contiguous) into LDS
    for (int i = d; i < CH * XDS; i += 384)
        xlds[i] = xdbl[rbase * XDS + i];

    float Adn[NS], h[NS];
    {
        const float4* ap4 = (const float4*)(A_log + d * NS);
        #pragma unroll
        for (int q = 0; q < 4; ++q) {
            const float4 v = ap4[q];
            Adn[q*4+0] = -__expf(v.x) * LOG2E;
            Adn[q*4+1] = -__expf(v.y) * LOG2E;
            Adn[q*4+2] = -__expf(v.z) * LOG2E;
            Adn[q*4+3] = -__expf(v.w) * LOG2E;
        }
    }
    float wdt[RK];
    #pragma unroll
    for (int r = 0; r < RK; ++r) wdt[r] = Wdt[r * DI + d];
    const float bdt = b_dt[d];
    #pragma unroll
    for (int n = 0; n < NS; ++n) h[n] = 0.f;

    // preload u (bf16, strided by KA) into registers
    float uu[CH];
    {
        const unsigned short* up = uA + rbase * KA + d;
        #pragma unroll
        for (int i = 0; i < CH; ++i) uu[i] = bf2f(up[(size_t)i * KA]);
    }
    __syncthreads();

    float sdlt = 0.f;
    #pragma unroll
    for (int i = 0; i < CH; ++i) {
        const float* xr = xlds + i * XDS;
        const float4 t0 = *(const float4*)(xr + 0);
        const float4 t1 = *(const float4*)(xr + 4);
        const float4 t2 = *(const float4*)(xr + 8);
        const float4 bb0 = *(const float4*)(xr + 12), bb1 = *(const float4*)(xr + 16);
        const float4 bb2 = *(const float4*)(xr + 20), bb3 = *(const float4*)(xr + 24);
        float t = bdt;
        t += t0.x * wdt[0] + t0.y * wdt[1] + t0.z * wdt[2]  + t0.w * wdt[3];
        t += t1.x * wdt[4] + t1.y * wdt[5] + t1.z * wdt[6]  + t1.w * wdt[7];
        t += t2.x * wdt[8] + t2.y * wdt[9] + t2.z * wdt[10] + t2.w * wdt[11];
        const float dlt = (t > 20.f) ? t : LN2 * __log2f(1.f + fexp2(t * LOG2E));
        const float du = dlt * uu[i];
        sdlt += dlt;
        const float bs[NS] = {bb0.x, bb0.y, bb0.z, bb0.w, bb1.x, bb1.y, bb1.z, bb1.w,
                              bb2.x, bb2.y, bb2.z, bb2.w, bb3.x, bb3.y, bb3.z, bb3.w};
        #pragma unroll
        for (int n = 0; n < NS; ++n) {
            const float a = fexp2(dlt * Adn[n]);
            h[n] = a * h[n] + du * bs[n];
        }
    }
    float* dst = AH + 2 * (((size_t)bc * DI + d) * NS);
    #pragma unroll
    for (int q = 0; q < 8; ++q) {
        const float ap0 = fexp2(sdlt * Adn[2*q]);
        const float ap1 = fexp2(sdlt * Adn[2*q+1]);
        *(float4*)(dst + 4 * q) = make_float4(ap0, h[2*q], ap1, h[2*q+1]);
    }
}

// ---------------------------------------------------------------------------
// Scan phase 2: sequential over NC chunks per (b,d,n) chain, 4-deep prefetch
// on interleaved float2 AH.  Writes chunk-entry state into AH[].x in-place.
// ---------------------------------------------------------------------------
__global__ __launch_bounds__(256) void scan_p2(float2* __restrict__ AH)
{
    const int gid = blockIdx.x * 256 + threadIdx.x;   // (b*DI + d)*NS + n
    const int dn = gid % (DI * NS);
    const int b  = gid / (DI * NS);
    const size_t base = (size_t)b * NC * DI * NS + dn;
    const size_t cs = (size_t)DI * NS;

    float2 buf[4];
    #pragma unroll
    for (int k = 0; k < 4; ++k) buf[k] = AH[base + (size_t)k * cs];

    float hin = 0.f;
    for (int c = 0; c < NC; c += 4) {
        #pragma unroll
        for (int k = 0; k < 4; ++k) {
            const int cn = (c + k + 4 < NC) ? (c + k + 4) : (NC - 1);  // clamp
            const float2 nxt = AH[base + (size_t)cn * cs];
            const float2 cur = buf[k];
            AH[base + (size_t)(c + k) * cs].x = hin;   // becomes Hin
            hin = cur.x * hin + cur.y;
            buf[k] = nxt;
        }
    }
}

// ---------------------------------------------------------------------------
// Scan phase 3 + LayerNorm + SiLU(z) gate, v4: operand-resident, one barrier.
// xdbl chunk staged in LDS; u/z preloaded to registers; phase A scans with
// per-wave partials in red[i][wave]; single sync; phase B normalizes+gates.
// ---------------------------------------------------------------------------
__global__ __launch_bounds__(384) void scan_p3_ln_v4(
    const unsigned short* __restrict__ uA, const unsigned short* __restrict__ z_bf,
    const float* __restrict__ xdbl, const float* __restrict__ AH,
    const float* __restrict__ A_log, const float* __restrict__ Wdt,
    const float* __restrict__ b_dt, const float* __restrict__ Dvec,
    const float* __restrict__ ln_g, const float* __restrict__ ln_b,
    unsigned short* __restrict__ yin_bf)
{
    __shared__ __align__(16) float xlds[CH * XDS];   // 4 KB
    __shared__ float red_s[CH][8], red_sq[CH][8];    // 1 KB
    const int d = threadIdx.x;
    const int bc = blockIdx.x;                        // b*NC + c
    const int b = bc / NC, c = bc % NC;
    const int wid = d >> 6, lane = d & 63;
    const size_t rbase = (size_t)(b * LL + c * CH);

    for (int i = d; i < CH * XDS; i += 384)
        xlds[i] = xdbl[rbase * XDS + i];

    float Adn[NS], h[NS];
    {
        const float4* ap4 = (const float4*)(A_log + d * NS);
        #pragma unroll
        for (int q = 0; q < 4; ++q) {
            const float4 v = ap4[q];
            Adn[q*4+0] = -__expf(v.x) * LOG2E;
            Adn[q*4+1] = -__expf(v.y) * LOG2E;
            Adn[q*4+2] = -__expf(v.z) * LOG2E;
            Adn[q*4+3] = -__expf(v.w) * LOG2E;
        }
    }
    float wdt[RK];
    #pragma unroll
    for (int r = 0; r < RK; ++r) wdt[r] = Wdt[r * DI + d];
    const float bdt = b_dt[d];
    {
        const float* hp = AH + 2 * (((size_t)bc * DI + d) * NS);
        #pragma unroll
        for (int q = 0; q < 8; ++q) {
            const float4 v = *(const float4*)(hp + 4 * q);
            h[2*q] = v.x; h[2*q+1] = v.z;      // .x slots hold Hin
        }
    }
    const float Dd = Dvec[d];
    const float lg = ln_g[d], lb = ln_b[d];

    // preload u and z (bf16) into registers
    float uu[CH], zz[CH];
    {
        const unsigned short* up = uA + rbase * KA + d;
        const unsigned short* zp = z_bf + rbase * DI + d;
        #pragma unroll
        for (int i = 0; i < CH; ++i) {
            uu[i] = bf2f(up[(size_t)i * KA]);
            zz[i] = bf2f(zp[(size_t)i * DI]);
        }
    }
    __syncthreads();   // xlds ready

    float accs[CH];
    // ---- Phase A: scan, no barriers ----
    #pragma unroll
    for (int i = 0; i < CH; ++i) {
        const float* xr = xlds + i * XDS;
        const float4 t0 = *(const float4*)(xr + 0);
        const float4 t1 = *(const float4*)(xr + 4);
        const float4 t2 = *(const float4*)(xr + 8);
        const float4 bb0 = *(const float4*)(xr + 12), bb1 = *(const float4*)(xr + 16);
        const float4 bb2 = *(const float4*)(xr + 20), bb3 = *(const float4*)(xr + 24);
        const float4 cc0 = *(const float4*)(xr + 28), cc1 = *(const float4*)(xr + 32);
        const float4 cc2 = *(const float4*)(xr + 36), cc3 = *(const float4*)(xr + 40);
        float t = bdt;
        t += t0.x * wdt[0] + t0.y * wdt[1] + t0.z * wdt[2]  + t0.w * wdt[3];
        t += t1.x * wdt[4] + t1.y * wdt[5] + t1.z * wdt[6]  + t1.w * wdt[7];
        t += t2.x * wdt[8] + t2.y * wdt[9] + t2.z * wdt[10] + t2.w * wdt[11];
        const float dlt = (t > 20.f) ? t : LN2 * __log2f(1.f + fexp2(t * LOG2E));
        const float du = dlt * uu[i];
        const float bs[NS] = {bb0.x, bb0.y, bb0.z, bb0.w, bb1.x, bb1.y, bb1.z, bb1.w,
                              bb2.x, bb2.y, bb2.z, bb2.w, bb3.x, bb3.y, bb3.z, bb3.w};
        const float cs[NS] = {cc0.x, cc0.y, cc0.z, cc0.w, cc1.x, cc1.y, cc1.z, cc1.w,
                              cc2.x, cc2.y, cc2.z, cc2.w, cc3.x, cc3.y, cc3.z, cc3.w};
        float acc = uu[i] * Dd;
        #pragma unroll
        for (int n = 0; n < NS; ++n) {
            const float a = fexp2(dlt * Adn[n]);
            h[n] = a * h[n] + du * bs[n];
            acc += h[n] * cs[n];
        }
        accs[i] = acc;
        float s = acc, sq = acc * acc;
        #pragma unroll
        for (int m = 1; m < 64; m <<= 1) {
            s  += __shfl_xor(s, m);
            sq += __shfl_xor(sq, m);
        }
        if (lane == 0) { red_s[i][wid] = s; red_sq[i][wid] = sq; }
    }

    __syncthreads();   // the only inter-phase barrier

    // ---- Phase B: normalize + gate + store ----
    unsigned short* yp = yin_bf + rbase * DI + d;
    #pragma unroll
    for (int i = 0; i < CH; ++i) {
        const float s = red_s[i][0] + red_s[i][1] + red_s[i][2]
                      + red_s[i][3] + red_s[i][4] + red_s[i][5];
        const float sq = red_sq[i][0] + red_sq[i][1] + red_sq[i][2]
                       + red_sq[i][3] + red_sq[i][4] + red_sq[i][5];
        const float mu = s * (1.f / DI);
        const float var = sq * (1.f / DI) - mu * mu;
        const float inv = rsqrtf(var + 1e-5f);
        const float yn = (accs[i] - mu) * inv * lg + lb;
        yp[(size_t)i * DI] = f2bf(yn * fsilu(zz[i]));
    }
}

// ---------------------------------------------------------------------------
extern "C" void kernel_launch(void* const* d_in, const int* in_sizes, int n_in,
                              void* d_out, int out_size, void* d_ws, size_t ws_size,
                              hipStream_t stream)
{
    const float* x      = (const float*)d_in[0];
    const float* prompt = (const float*)d_in[1];
    const float* W_in   = (const float*)d_in[2];
    const float* conv_w = (const float*)d_in[3];
    const float* conv_b = (const float*)d_in[4];
    const float* Wx     = (const float*)d_in[5];
    const float* Wdt    = (const float*)d_in[6];
    const float* b_dt   = (const float*)d_in[7];
    const float* A_log  = (const float*)d_in[8];
    const float* Dvec   = (const float*)d_in[9];
    const float* Wp     = (const float*)d_in[10];
    const float* ln_g   = (const float*)d_in[11];
    const float* ln_b   = (const float*)d_in[12];
    const float* Wout   = (const float*)d_in[13];
    float* out = (float*)d_out;

    char* p = (char*)d_ws;
    float* xi = (float*)p;                 p += (size_t)ROWS * DI * 4;             // 25.2 MB
    unsigned short* z_bf = (unsigned short*)p;  p += (size_t)(ROWS + 1) * DI * 2;  // 12.6 MB
    unsigned short* Across = (unsigned short*)p; p += (size_t)(ROWS + 1) * KA * 2; // 18.9 MB
    float* xdbl = (float*)p;               p += (size_t)(ROWS + 1) * XDS * 4;      // 4.2 MB
    char* ahreg = p;
    float* AH = (float*)p;                 p += (size_t)BB * NC * DI * NS * 8;     // 50.3 MB
    unsigned short* WinT  = (unsigned short*)p;  p += (size_t)(2 * DI) * DM * 2;   // 288 KB
    unsigned short* BxT   = (unsigned short*)p;  p += (size_t)XDS * KA * 2;        // 72 KB
    unsigned short* WoutT = (unsigned short*)p;  p += (size_t)DM * DI * 2;         // 144 KB
    // x_bf lives inside AH region (dead after gemm1, before scan_p1 writes AH)
    unsigned short* x_bf = (unsigned short*)ahreg;                                 // 6.3 MB
    unsigned short* yin_bf = (unsigned short*)xi;  // xi dead after conv

    // 0. conversions / weight builds (independent)
    f32_to_bf16_vec<<<(ROWS * DM / 4 + 255) / 256, 256, 0, stream>>>(x, x_bf, ROWS * DM / 4);
    prompt_to_across<<<(ROWS * (DM / 4) + 255) / 256, 256, 0, stream>>>(prompt, Across);
    build_bt<<<(2 * DI * DM + 255) / 256, 256, 0, stream>>>(W_in, WinT, DM, 2 * DI, 2 * DI);
    build_bxt<<<(XDS * KA + 255) / 256, 256, 0, stream>>>(Wx, Wp, BxT);
    build_bt<<<(DM * DI + 255) / 256, 256, 0, stream>>>(Wout, WoutT, DI, DM, DM);

    // 1. xz = x @ W_in -> xi (f32) | z_bf (bf16)   (M=16384, N=768, K=192)
    {
        dim3 g(ROWS / 64, (2 * DI) / 64);
        gemm_bf16_mfma<true><<<g, 256, 0, stream>>>(x_bf, WinT, xi, z_bf, ROWS, 2 * DI, DM, DI);
    }
    // 2. depthwise conv + bias + SiLU -> u_bf into Across cols 0..383
    conv_dw_silu<<<(BB * HH * WW * 96) / 256, 256, 0, stream>>>(xi, conv_w, conv_b, Across);
    // 3. xdbl = [u | prompt] @ B'  (M=16384, N=64, K=576; Cs includes prompt@Wp)
    {
        dim3 g(ROWS / 64, 1);
        gemm_bf16_mfma<false><<<g, 256, 0, stream>>>(Across, BxT, xdbl, nullptr, ROWS, XDS, KA, 0);
    }
    // 4-6. chunked selective scan (operand-resident; p2 writes Hin into AH[].x)
    scan_p1_v6<<<BB * NC, 384, 0, stream>>>(Across, xdbl, A_log, Wdt, b_dt, AH);
    scan_p2<<<(BB * DI * NS) / 256, 256, 0, stream>>>((float2*)AH);
    // 7. scan replay + LayerNorm + SiLU(z) gate -> yin_bf (reuses xi)
    scan_p3_ln_v4<<<BB * NC, 384, 0, stream>>>(Across, z_bf, xdbl, AH, A_log, Wdt,
                                               b_dt, Dvec, ln_g, ln_b, yin_bf);
    // 8. out = yin @ Wout  (M=16384, N=192, K=384)
    {
        dim3 g(ROWS / 64, DM / 64);
        gemm_bf16_mfma<false><<<g, 256, 0, stream>>>(yin_bf, WoutT, out, nullptr, ROWS, DM, DI, 0);
    }
}

// Round 12
// 288.431 us; speedup vs baseline: 1.0040x; 1.0040x over previous
//
#include <hip/hip_runtime.h>
#include <hip/hip_bf16.h>

// Problem constants
#define BB 4
#define HH 64
#define WW 64
#define LL 4096           // HH*WW
#define DM 192            // D_MODEL
#define DI 384            // D_INNER
#define NS 16             // D_STATE
#define RK 12             // DT_RANK
#define NC 256            // number of scan chunks
#define CH 16             // chunk length (NC*CH == LL)
#define ROWS 16384        // BB*LL
#define XDS 64            // xdbl row stride (44 cols meaningful)
#define KA 576            // fused A' width: 384 u_bf | 192 prompt_bf
#define LOG2E 1.44269504f
#define LN2   0.69314718f

typedef __bf16 bf16x8 __attribute__((ext_vector_type(8)));
typedef float  f32x4  __attribute__((ext_vector_type(4)));

#if defined(__has_builtin)
#if __has_builtin(__builtin_amdgcn_exp2f)
#define fexp2(x) __builtin_amdgcn_exp2f(x)
#else
#define fexp2(x) exp2f(x)
#endif
#else
#define fexp2(x) exp2f(x)
#endif

__device__ __forceinline__ float fsilu(float x) {
    return x / (1.0f + __expf(-x));
}

// f32 -> bf16 (RNE)
__device__ __forceinline__ unsigned short f2bf(float f) {
    unsigned int u = __float_as_uint(f);
    unsigned int r = (u + 0x7fffu + ((u >> 16) & 1u)) >> 16;
    return (unsigned short)r;
}
// bf16 -> f32
__device__ __forceinline__ float bf2f(unsigned short v) {
    return __uint_as_float((unsigned int)v << 16);
}

// ---------------------------------------------------------------------------
// x (ROWS x DM f32) -> x_bf (bf16, contiguous)
// ---------------------------------------------------------------------------
__global__ __launch_bounds__(256) void f32_to_bf16_vec(
    const float* __restrict__ src, unsigned short* __restrict__ dst, int n4)
{
    int i = blockIdx.x * 256 + threadIdx.x;
    if (i < n4) {
        float4 v = ((const float4*)src)[i];
        ((ushort4*)dst)[i] = make_ushort4(f2bf(v.x), f2bf(v.y), f2bf(v.z), f2bf(v.w));
    }
}

// ---------------------------------------------------------------------------
// prompt (ROWS x DM f32) -> Across cols 384..575 (stride KA, bf16)
// ---------------------------------------------------------------------------
__global__ __launch_bounds__(256) void prompt_to_across(
    const float* __restrict__ prompt, unsigned short* __restrict__ Across)
{
    int i4 = blockIdx.x * 256 + threadIdx.x;     // ROWS * 48
    if (i4 >= ROWS * (DM / 4)) return;
    int row = i4 / (DM / 4), c4 = i4 % (DM / 4);
    float4 v = ((const float4*)prompt)[i4];
    *(ushort4*)&Across[(size_t)row * KA + DI + c4 * 4] =
        make_ushort4(f2bf(v.x), f2bf(v.y), f2bf(v.z), f2bf(v.w));
}

// ---------------------------------------------------------------------------
// Build transposed bf16 weight: src (K x Nsrc f32) -> dst (Nrows x K bf16)
// ---------------------------------------------------------------------------
__global__ __launch_bounds__(256) void build_bt(
    const float* __restrict__ src, unsigned short* __restrict__ dst,
    int K, int Nsrc, int Nrows)
{
    int idx = blockIdx.x * 256 + threadIdx.x;
    if (idx >= Nrows * K) return;
    int n = idx / K, k = idx % K;
    dst[idx] = (n < Nsrc) ? f2bf(src[k * Nsrc + n]) : (unsigned short)0;
}

// ---------------------------------------------------------------------------
// Build fused B' (XDS rows x KA cols, transposed N x K)
// ---------------------------------------------------------------------------
__global__ __launch_bounds__(256) void build_bxt(
    const float* __restrict__ Wx, const float* __restrict__ Wp,
    unsigned short* __restrict__ dst)
{
    int idx = blockIdx.x * 256 + threadIdx.x;    // XDS * KA
    if (idx >= XDS * KA) return;
    int n = idx / KA, k = idx % KA;
    float v = 0.f;
    if (k < DI) { if (n < 44) v = Wx[k * 44 + n]; }
    else        { if (n >= 28 && n < 44) v = Wp[(k - DI) * NS + (n - 28)]; }
    dst[idx] = f2bf(v);
}

// ---------------------------------------------------------------------------
// bf16 MFMA GEMM: C = A(MxK bf16) * BT^T (BT is N x K bf16).  64x64 tile,
// BK=32, 4 waves x (2x2) 16x16x32 fragments, LDS stride 80B.
// SPLIT: cols < halfN -> C0 (f32, stride halfN); cols >= halfN -> C1z (bf16).
// ---------------------------------------------------------------------------
template<bool SPLIT>
__global__ __launch_bounds__(256) void gemm_bf16_mfma(
    const unsigned short* __restrict__ A, const unsigned short* __restrict__ BT,
    float* __restrict__ C0, unsigned short* __restrict__ C1z,
    int M, int N, int K, int halfN)
{
    __shared__ __align__(16) char lds[64 * 80 * 2];
    char* As = lds;
    char* Bs = lds + 64 * 80;
    const int tid = threadIdx.x;
    const int w = tid >> 6, lane = tid & 63;
    const int wm = w >> 1, wn = w & 1;
    const int row0 = blockIdx.x * 64, col0 = blockIdx.y * 64;
    const int r = tid >> 2, cch = tid & 3;
    const int l15 = lane & 15, k8 = lane >> 4;

    f32x4 acc[2][2] = {};
    for (int k0 = 0; k0 < K; k0 += 32) {
        *(float4*)(As + r * 80 + cch * 16) =
            *(const float4*)(A + (size_t)(row0 + r) * K + k0 + cch * 8);
        *(float4*)(Bs + r * 80 + cch * 16) =
            *(const float4*)(BT + (size_t)(col0 + r) * K + k0 + cch * 8);
        __syncthreads();
        bf16x8 a0 = *(const bf16x8*)(As + (wm * 32 +      l15) * 80 + k8 * 16);
        bf16x8 a1 = *(const bf16x8*)(As + (wm * 32 + 16 + l15) * 80 + k8 * 16);
        bf16x8 b0 = *(const bf16x8*)(Bs + (wn * 32 +      l15) * 80 + k8 * 16);
        bf16x8 b1 = *(const bf16x8*)(Bs + (wn * 32 + 16 + l15) * 80 + k8 * 16);
        acc[0][0] = __builtin_amdgcn_mfma_f32_16x16x32_bf16(a0, b0, acc[0][0], 0, 0, 0);
        acc[0][1] = __builtin_amdgcn_mfma_f32_16x16x32_bf16(a0, b1, acc[0][1], 0, 0, 0);
        acc[1][0] = __builtin_amdgcn_mfma_f32_16x16x32_bf16(a1, b0, acc[1][0], 0, 0, 0);
        acc[1][1] = __builtin_amdgcn_mfma_f32_16x16x32_bf16(a1, b1, acc[1][1], 0, 0, 0);
        __syncthreads();
    }

    if (SPLIT && col0 >= halfN) {
        const int cbase = col0 - halfN;
        #pragma unroll
        for (int fm = 0; fm < 2; ++fm)
            #pragma unroll
            for (int fn = 0; fn < 2; ++fn)
                #pragma unroll
                for (int reg = 0; reg < 4; ++reg) {
                    int row = row0 + wm * 32 + fm * 16 + k8 * 4 + reg;
                    int col = cbase + wn * 32 + fn * 16 + l15;
                    C1z[(size_t)row * halfN + col] = f2bf(acc[fm][fn][reg]);
                }
    } else {
        const int cstride = SPLIT ? halfN : N;
        #pragma unroll
        for (int fm = 0; fm < 2; ++fm)
            #pragma unroll
            for (int fn = 0; fn < 2; ++fn)
                #pragma unroll
                for (int reg = 0; reg < 4; ++reg) {
                    int row = row0 + wm * 32 + fm * 16 + k8 * 4 + reg;
                    int col = col0 + wn * 32 + fn * 16 + l15;
                    C0[(size_t)row * cstride + col] = acc[fm][fn][reg];
                }
    }
}

// ---------------------------------------------------------------------------
// Depthwise 3x3 conv (channel-last), bias + SiLU.
// xi (B,H,W,DI f32) -> u_bf (bf16) written into Across cols 0..383 (stride KA)
// ---------------------------------------------------------------------------
__global__ __launch_bounds__(256) void conv_dw_silu(
    const float* __restrict__ xi, const float* __restrict__ conv_w,
    const float* __restrict__ conv_b, unsigned short* __restrict__ Across)
{
    int idx = blockIdx.x * 256 + threadIdx.x;   // total BB*HH*WW*96
    int c4 = idx % 96;
    int rest = idx / 96;
    int w = rest % WW; rest /= WW;
    int h = rest % HH;
    int b = rest / HH;
    int c = c4 * 4;

    float wgt[4][9];
    #pragma unroll
    for (int q = 0; q < 4; ++q)
        #pragma unroll
        for (int t = 0; t < 9; ++t)
            wgt[q][t] = conv_w[(c + q) * 9 + t];

    float4 acc = *(const float4*)&conv_b[c];
    #pragma unroll
    for (int kh = 0; kh < 3; ++kh) {
        int hh = h + kh - 1;
        if ((unsigned)hh >= HH) continue;
        #pragma unroll
        for (int kw = 0; kw < 3; ++kw) {
            int ww = w + kw - 1;
            if ((unsigned)ww >= WW) continue;
            const float4 xv = *(const float4*)&xi[(((size_t)(b * HH + hh)) * WW + ww) * DI + c];
            int t = kh * 3 + kw;
            acc.x += xv.x * wgt[0][t];
            acc.y += xv.y * wgt[1][t];
            acc.z += xv.z * wgt[2][t];
            acc.w += xv.w * wgt[3][t];
        }
    }
    acc.x = fsilu(acc.x); acc.y = fsilu(acc.y);
    acc.z = fsilu(acc.z); acc.w = fsilu(acc.w);
    size_t off = (((size_t)b * LL) + h * WW + w) * KA + c;
    *(ushort4*)&Across[off] = make_ushort4(f2bf(acc.x), f2bf(acc.y), f2bf(acc.z), f2bf(acc.w));
}

// ---------------------------------------------------------------------------
// Scan phase 1 v7: one block = one (b,chunk), 384 threads (thread = d).
// xdbl chunk staged in LDS once; per-step operands read from LDS at use
// (no register arrays); u read with 1-deep rolling global prefetch.
// Writes interleaved AH pairs {ap, h}.
// ---------------------------------------------------------------------------
__global__ __launch_bounds__(384) void scan_p1_v7(
    const unsigned short* __restrict__ uA, const float* __restrict__ xdbl,
    const float* __restrict__ A_log, const float* __restrict__ Wdt,
    const float* __restrict__ b_dt, float* __restrict__ AH)
{
    __shared__ __align__(16) float xlds[CH * XDS];   // 4 KB
    const int d = threadIdx.x;
    const int bc = blockIdx.x;                        // b*NC + c
    const int b = bc / NC, c = bc % NC;
    const size_t rbase = (size_t)(b * LL + c * CH);

    for (int i = d; i < CH * XDS; i += 384)
        xlds[i] = xdbl[rbase * XDS + i];

    float Adn[NS], h[NS];
    {
        const float4* ap4 = (const float4*)(A_log + d * NS);
        #pragma unroll
        for (int q = 0; q < 4; ++q) {
            const float4 v = ap4[q];
            Adn[q*4+0] = -__expf(v.x) * LOG2E;
            Adn[q*4+1] = -__expf(v.y) * LOG2E;
            Adn[q*4+2] = -__expf(v.z) * LOG2E;
            Adn[q*4+3] = -__expf(v.w) * LOG2E;
        }
    }
    float wdt[RK];
    #pragma unroll
    for (int r = 0; r < RK; ++r) wdt[r] = Wdt[r * DI + d];
    const float bdt = b_dt[d];
    #pragma unroll
    for (int n = 0; n < NS; ++n) h[n] = 0.f;

    const unsigned short* up = uA + rbase * KA + d;
    float uu = bf2f(up[0]);
    __syncthreads();   // xlds ready

    float sdlt = 0.f;
    #pragma unroll
    for (int i = 0; i < CH; ++i) {
        const float uu_n = bf2f(up[(size_t)(i + 1) * KA]);  // OOB-by-one: padded row
        const float* xr = xlds + i * XDS;
        const float4 t0 = *(const float4*)(xr + 0);
        const float4 t1 = *(const float4*)(xr + 4);
        const float4 t2 = *(const float4*)(xr + 8);
        const float4 bb0 = *(const float4*)(xr + 12), bb1 = *(const float4*)(xr + 16);
        const float4 bb2 = *(const float4*)(xr + 20), bb3 = *(const float4*)(xr + 24);
        float t = bdt;
        t += t0.x * wdt[0] + t0.y * wdt[1] + t0.z * wdt[2]  + t0.w * wdt[3];
        t += t1.x * wdt[4] + t1.y * wdt[5] + t1.z * wdt[6]  + t1.w * wdt[7];
        t += t2.x * wdt[8] + t2.y * wdt[9] + t2.z * wdt[10] + t2.w * wdt[11];
        const float dlt = (t > 20.f) ? t : LN2 * __log2f(1.f + fexp2(t * LOG2E));
        const float du = dlt * uu;
        sdlt += dlt;
        const float bs[NS] = {bb0.x, bb0.y, bb0.z, bb0.w, bb1.x, bb1.y, bb1.z, bb1.w,
                              bb2.x, bb2.y, bb2.z, bb2.w, bb3.x, bb3.y, bb3.z, bb3.w};
        #pragma unroll
        for (int n = 0; n < NS; ++n) {
            const float a = fexp2(dlt * Adn[n]);
            h[n] = a * h[n] + du * bs[n];
        }
        uu = uu_n;
    }
    float* dst = AH + 2 * (((size_t)bc * DI + d) * NS);
    #pragma unroll
    for (int q = 0; q < 8; ++q) {
        const float ap0 = fexp2(sdlt * Adn[2*q]);
        const float ap1 = fexp2(sdlt * Adn[2*q+1]);
        *(float4*)(dst + 4 * q) = make_float4(ap0, h[2*q], ap1, h[2*q+1]);
    }
}

// ---------------------------------------------------------------------------
// Scan phase 2 v2: sequential over NC chunks per (b,d,n) chain, 4-deep
// prefetch on interleaved float2 AH.  Writes chunk-entry state to COMPACT
// Hinc buffer (p3 then reads 16 floats, not 32).
// ---------------------------------------------------------------------------
__global__ __launch_bounds__(256) void scan_p2_v2(
    const float2* __restrict__ AH, float* __restrict__ Hinc)
{
    const int gid = blockIdx.x * 256 + threadIdx.x;   // (b*DI + d)*NS + n
    const int dn = gid % (DI * NS);
    const int b  = gid / (DI * NS);
    const size_t base = (size_t)b * NC * DI * NS + dn;
    const size_t cs = (size_t)DI * NS;

    float2 buf[4];
    #pragma unroll
    for (int k = 0; k < 4; ++k) buf[k] = AH[base + (size_t)k * cs];

    float hin = 0.f;
    for (int c = 0; c < NC; c += 4) {
        #pragma unroll
        for (int k = 0; k < 4; ++k) {
            const int cn = (c + k + 4 < NC) ? (c + k + 4) : (NC - 1);  // clamp
            const float2 nxt = AH[base + (size_t)cn * cs];
            const float2 cur = buf[k];
            Hinc[base + (size_t)(c + k) * cs] = hin;
            hin = cur.x * hin + cur.y;
            buf[k] = nxt;
        }
    }
}

// ---------------------------------------------------------------------------
// Scan phase 3 + LayerNorm + SiLU(z) gate, v5: parity-barrier rolling shape
// (measured-best) + LDS-staged xdbl + compact Hinc + rolling u/z prefetch.
// No per-thread arrays beyond h/Adn/wdt -> VGPR back under 64.
// ---------------------------------------------------------------------------
__global__ __launch_bounds__(384) void scan_p3_ln_v5(
    const unsigned short* __restrict__ uA, const unsigned short* __restrict__ z_bf,
    const float* __restrict__ xdbl, const float* __restrict__ Hinc,
    const float* __restrict__ A_log, const float* __restrict__ Wdt,
    const float* __restrict__ b_dt, const float* __restrict__ Dvec,
    const float* __restrict__ ln_g, const float* __restrict__ ln_b,
    unsigned short* __restrict__ yin_bf)
{
    __shared__ __align__(16) float xlds[CH * XDS];   // 4 KB
    __shared__ float red_s[2][8], red_sq[2][8];
    const int d = threadIdx.x;
    const int bc = blockIdx.x;                        // b*NC + c
    const int b = bc / NC, c = bc % NC;
    const int wid = d >> 6, lane = d & 63;
    const size_t rbase = (size_t)(b * LL + c * CH);

    for (int i = d; i < CH * XDS; i += 384)
        xlds[i] = xdbl[rbase * XDS + i];

    float Adn[NS], h[NS];
    {
        const float4* ap4 = (const float4*)(A_log + d * NS);
        #pragma unroll
        for (int q = 0; q < 4; ++q) {
            const float4 v = ap4[q];
            Adn[q*4+0] = -__expf(v.x) * LOG2E;
            Adn[q*4+1] = -__expf(v.y) * LOG2E;
            Adn[q*4+2] = -__expf(v.z) * LOG2E;
            Adn[q*4+3] = -__expf(v.w) * LOG2E;
        }
    }
    float wdt[RK];
    #pragma unroll
    for (int r = 0; r < RK; ++r) wdt[r] = Wdt[r * DI + d];
    const float bdt = b_dt[d];
    {
        const float* hp = Hinc + ((size_t)bc * DI + d) * NS;
        #pragma unroll
        for (int q = 0; q < 4; ++q) {
            const float4 v = *(const float4*)(hp + 4 * q);
            h[q*4] = v.x; h[q*4+1] = v.y; h[q*4+2] = v.z; h[q*4+3] = v.w;
        }
    }
    const float Dd = Dvec[d];
    const float lg = ln_g[d], lb = ln_b[d];

    const unsigned short* up = uA + rbase * KA + d;
    const unsigned short* zp = z_bf + rbase * DI + d;
    unsigned short* yp = yin_bf + rbase * DI + d;

    float uu = bf2f(up[0]), zz = bf2f(zp[0]);
    __syncthreads();   // xlds ready

    #pragma unroll
    for (int i = 0; i < CH; ++i) {
        // rolling prefetch (OOB-by-one on last iter: padded rows)
        const float uu_n = bf2f(up[(size_t)(i + 1) * KA]);
        const float zz_n = bf2f(zp[(size_t)(i + 1) * DI]);
        const float* xr = xlds + i * XDS;
        const float4 t0 = *(const float4*)(xr + 0);
        const float4 t1 = *(const float4*)(xr + 4);
        const float4 t2 = *(const float4*)(xr + 8);
        const float4 bb0 = *(const float4*)(xr + 12), bb1 = *(const float4*)(xr + 16);
        const float4 bb2 = *(const float4*)(xr + 20), bb3 = *(const float4*)(xr + 24);
        const float4 cc0 = *(const float4*)(xr + 28), cc1 = *(const float4*)(xr + 32);
        const float4 cc2 = *(const float4*)(xr + 36), cc3 = *(const float4*)(xr + 40);
        float t = bdt;
        t += t0.x * wdt[0] + t0.y * wdt[1] + t0.z * wdt[2]  + t0.w * wdt[3];
        t += t1.x * wdt[4] + t1.y * wdt[5] + t1.z * wdt[6]  + t1.w * wdt[7];
        t += t2.x * wdt[8] + t2.y * wdt[9] + t2.z * wdt[10] + t2.w * wdt[11];
        const float dlt = (t > 20.f) ? t : LN2 * __log2f(1.f + fexp2(t * LOG2E));
        const float du = dlt * uu;
        const float bs[NS] = {bb0.x, bb0.y, bb0.z, bb0.w, bb1.x, bb1.y, bb1.z, bb1.w,
                              bb2.x, bb2.y, bb2.z, bb2.w, bb3.x, bb3.y, bb3.z, bb3.w};
        const float cs[NS] = {cc0.x, cc0.y, cc0.z, cc0.w, cc1.x, cc1.y, cc1.z, cc1.w,
                              cc2.x, cc2.y, cc2.z, cc2.w, cc3.x, cc3.y, cc3.z, cc3.w};
        float acc = uu * Dd;
        #pragma unroll
        for (int n = 0; n < NS; ++n) {
            const float a = fexp2(dlt * Adn[n]);
            h[n] = a * h[n] + du * bs[n];
            acc += h[n] * cs[n];
        }
        // block LayerNorm reduce over 384 d's (parity LDS double-buffer)
        float s = acc, sq = acc * acc;
        #pragma unroll
        for (int m = 1; m < 64; m <<= 1) {
            s  += __shfl_xor(s, m);
            sq += __shfl_xor(sq, m);
        }
        const int par = i & 1;
        if (lane == 0) { red_s[par][wid] = s; red_sq[par][wid] = sq; }
        __syncthreads();
        s = red_s[par][0] + red_s[par][1] + red_s[par][2]
          + red_s[par][3] + red_s[par][4] + red_s[par][5];
        sq = red_sq[par][0] + red_sq[par][1] + red_sq[par][2]
           + red_sq[par][3] + red_sq[par][4] + red_sq[par][5];
        const float mu = s * (1.f / DI);
        const float var = sq * (1.f / DI) - mu * mu;
        const float inv = rsqrtf(var + 1e-5f);
        const float yn = (acc - mu) * inv * lg + lb;
        yp[(size_t)i * DI] = f2bf(yn * fsilu(zz));

        uu = uu_n; zz = zz_n;
    }
}

// ---------------------------------------------------------------------------
extern "C" void kernel_launch(void* const* d_in, const int* in_sizes, int n_in,
                              void* d_out, int out_size, void* d_ws, size_t ws_size,
                              hipStream_t stream)
{
    const float* x      = (const float*)d_in[0];
    const float* prompt = (const float*)d_in[1];
    const float* W_in   = (const float*)d_in[2];
    const float* conv_w = (const float*)d_in[3];
    const float* conv_b = (const float*)d_in[4];
    const float* Wx     = (const float*)d_in[5];
    const float* Wdt    = (const float*)d_in[6];
    const float* b_dt   = (const float*)d_in[7];
    const float* A_log  = (const float*)d_in[8];
    const float* Dvec   = (const float*)d_in[9];
    const float* Wp     = (const float*)d_in[10];
    const float* ln_g   = (const float*)d_in[11];
    const float* ln_b   = (const float*)d_in[12];
    const float* Wout   = (const float*)d_in[13];
    float* out = (float*)d_out;

    char* p = (char*)d_ws;
    float* xi = (float*)p;                 p += (size_t)ROWS * DI * 4;             // 25.2 MB
    unsigned short* z_bf = (unsigned short*)p;  p += (size_t)(ROWS + 1) * DI * 2;  // 12.6 MB
    unsigned short* Across = (unsigned short*)p; p += (size_t)(ROWS + 1) * KA * 2; // 18.9 MB
    float* xdbl = (float*)p;               p += (size_t)(ROWS + 1) * XDS * 4;      // 4.2 MB
    char* ahreg = p;
    float* AH = (float*)p;                 p += (size_t)BB * NC * DI * NS * 8;     // 50.3 MB
    float* Hinc = (float*)p;               p += (size_t)BB * NC * DI * NS * 4;     // 25.2 MB
    unsigned short* WinT  = (unsigned short*)p;  p += (size_t)(2 * DI) * DM * 2;   // 288 KB
    unsigned short* BxT   = (unsigned short*)p;  p += (size_t)XDS * KA * 2;        // 72 KB
    unsigned short* WoutT = (unsigned short*)p;  p += (size_t)DM * DI * 2;         // 144 KB
    // x_bf lives inside AH region (dead after gemm1, before scan_p1 writes AH)
    unsigned short* x_bf = (unsigned short*)ahreg;                                 // 6.3 MB
    unsigned short* yin_bf = (unsigned short*)xi;  // xi dead after conv

    // 0. conversions / weight builds (independent)
    f32_to_bf16_vec<<<(ROWS * DM / 4 + 255) / 256, 256, 0, stream>>>(x, x_bf, ROWS * DM / 4);
    prompt_to_across<<<(ROWS * (DM / 4) + 255) / 256, 256, 0, stream>>>(prompt, Across);
    build_bt<<<(2 * DI * DM + 255) / 256, 256, 0, stream>>>(W_in, WinT, DM, 2 * DI, 2 * DI);
    build_bxt<<<(XDS * KA + 255) / 256, 256, 0, stream>>>(Wx, Wp, BxT);
    build_bt<<<(DM * DI + 255) / 256, 256, 0, stream>>>(Wout, WoutT, DI, DM, DM);

    // 1. xz = x @ W_in -> xi (f32) | z_bf (bf16)   (M=16384, N=768, K=192)
    {
        dim3 g(ROWS / 64, (2 * DI) / 64);
        gemm_bf16_mfma<true><<<g, 256, 0, stream>>>(x_bf, WinT, xi, z_bf, ROWS, 2 * DI, DM, DI);
    }
    // 2. depthwise conv + bias + SiLU -> u_bf into Across cols 0..383
    conv_dw_silu<<<(BB * HH * WW * 96) / 256, 256, 0, stream>>>(xi, conv_w, conv_b, Across);
    // 3. xdbl = [u | prompt] @ B'  (M=16384, N=64, K=576; Cs includes prompt@Wp)
    {
        dim3 g(ROWS / 64, 1);
        gemm_bf16_mfma<false><<<g, 256, 0, stream>>>(Across, BxT, xdbl, nullptr, ROWS, XDS, KA, 0);
    }
    // 4-6. chunked selective scan (p2 writes compact Hinc)
    scan_p1_v7<<<BB * NC, 384, 0, stream>>>(Across, xdbl, A_log, Wdt, b_dt, AH);
    scan_p2_v2<<<(BB * DI * NS) / 256, 256, 0, stream>>>((const float2*)AH, Hinc);
    // 7. scan replay + LayerNorm + SiLU(z) gate -> yin_bf (reuses xi)
    scan_p3_ln_v5<<<BB * NC, 384, 0, stream>>>(Across, z_bf, xdbl, Hinc, A_log, Wdt,
                                               b_dt, Dvec, ln_g, ln_b, yin_bf);
    // 8. out = yin @ Wout  (M=16384, N=192, K=384)
    {
        dim3 g(ROWS / 64, DM / 64);
        gemm_bf16_mfma<false><<<g, 256, 0, stream>>>(yin_bf, WoutT, out, nullptr, ROWS, DM, DI, 0);
    }
}

// Round 14
// 271.842 us; speedup vs baseline: 1.0653x; 1.0610x over previous
//
#include <hip/hip_runtime.h>
#include <hip/hip_bf16.h>

// Problem constants
#define BB 4
#define HH 64
#define WW 64
#define LL 4096           // HH*WW
#define DM 192            // D_MODEL
#define DI 384            // D_INNER
#define NS 16             // D_STATE
#define RK 12             // DT_RANK
#define NC 256            // number of scan chunks
#define CH 16             // chunk length (NC*CH == LL)
#define ROWS 16384        // BB*LL
#define XDS 64            // xdbl row stride (cols 12..43 meaningful)
#define KA 576            // fused A' width: 384 u_bf | 192 prompt_bf
#define NXE 448           // extended GEMM N: 64 xdbl | 384 delta
#define LOG2E 1.44269504f
#define LN2   0.69314718f

typedef __bf16 bf16x8 __attribute__((ext_vector_type(8)));
typedef float  f32x4  __attribute__((ext_vector_type(4)));

#if defined(__has_builtin)
#if __has_builtin(__builtin_amdgcn_exp2f)
#define fexp2(x) __builtin_amdgcn_exp2f(x)
#else
#define fexp2(x) exp2f(x)
#endif
#else
#define fexp2(x) exp2f(x)
#endif

__device__ __forceinline__ float fsilu(float x) {
    return x / (1.0f + __expf(-x));
}

// f32 -> bf16 (RNE)
__device__ __forceinline__ unsigned short f2bf(float f) {
    unsigned int u = __float_as_uint(f);
    unsigned int r = (u + 0x7fffu + ((u >> 16) & 1u)) >> 16;
    return (unsigned short)r;
}
// bf16 -> f32
__device__ __forceinline__ float bf2f(unsigned short v) {
    return __uint_as_float((unsigned int)v << 16);
}

// ---------------------------------------------------------------------------
// x (ROWS x DM f32) -> x_bf (bf16, contiguous)
// ---------------------------------------------------------------------------
__global__ __launch_bounds__(256) void f32_to_bf16_vec(
    const float* __restrict__ src, unsigned short* __restrict__ dst, int n4)
{
    int i = blockIdx.x * 256 + threadIdx.x;
    if (i < n4) {
        float4 v = ((const float4*)src)[i];
        ((ushort4*)dst)[i] = make_ushort4(f2bf(v.x), f2bf(v.y), f2bf(v.z), f2bf(v.w));
    }
}

// ---------------------------------------------------------------------------
// prompt (ROWS x DM f32) -> Across cols 384..575 (stride KA, bf16)
// ---------------------------------------------------------------------------
__global__ __launch_bounds__(256) void prompt_to_across(
    const float* __restrict__ prompt, unsigned short* __restrict__ Across)
{
    int i4 = blockIdx.x * 256 + threadIdx.x;     // ROWS * 48
    if (i4 >= ROWS * (DM / 4)) return;
    int row = i4 / (DM / 4), c4 = i4 % (DM / 4);
    float4 v = ((const float4*)prompt)[i4];
    *(ushort4*)&Across[(size_t)row * KA + DI + c4 * 4] =
        make_ushort4(f2bf(v.x), f2bf(v.y), f2bf(v.z), f2bf(v.w));
}

// ---------------------------------------------------------------------------
// Build transposed bf16 weight: src (K x Nsrc f32) -> dst (Nrows x K bf16)
// ---------------------------------------------------------------------------
__global__ __launch_bounds__(256) void build_bt(
    const float* __restrict__ src, unsigned short* __restrict__ dst,
    int K, int Nsrc, int Nrows)
{
    int idx = blockIdx.x * 256 + threadIdx.x;
    if (idx >= Nrows * K) return;
    int n = idx / K, k = idx % K;
    dst[idx] = (n < Nsrc) ? f2bf(src[k * Nsrc + n]) : (unsigned short)0;
}

// ---------------------------------------------------------------------------
// Build extended fused B' (NXE rows x KA cols, transposed N x K):
//   n <  64 : k<384 -> Wx[k][n] (n<44); k>=384 -> Wp[k-384][n-28] (28<=n<44)
//   n >= 64 : k<384 -> Wcomp[k][n-64] = sum_r Wx[k][r]*Wdt[r][n-64]; else 0
// (composed delta projection: delta_pre = u @ Wcomp, prompt contributes 0)
// ---------------------------------------------------------------------------
__global__ __launch_bounds__(256) void build_bxt_ext(
    const float* __restrict__ Wx, const float* __restrict__ Wp,
    const float* __restrict__ Wdt, unsigned short* __restrict__ dst)
{
    int idx = blockIdx.x * 256 + threadIdx.x;    // NXE * KA
    if (idx >= NXE * KA) return;
    int n = idx / KA, k = idx % KA;
    float v = 0.f;
    if (n < 64) {
        if (k < DI) { if (n < 44) v = Wx[k * 44 + n]; }
        else        { if (n >= 28 && n < 44) v = Wp[(k - DI) * NS + (n - 28)]; }
    } else {
        if (k < DI) {
            const int d = n - 64;
            #pragma unroll
            for (int r = 0; r < RK; ++r)
                v += Wx[k * 44 + r] * Wdt[r * DI + d];
        }
    }
    dst[idx] = f2bf(v);
}

// ---------------------------------------------------------------------------
// bf16 MFMA GEMM: C = A(MxK bf16) * BT^T (BT is N x K bf16).  64x64 tile,
// BK=32, 4 waves x (2x2) 16x16x32 fragments, LDS stride 80B.
// MODE 0: C0 f32, stride N (output GEMM)
// MODE 1: dual bf16 split at halfN -> D0 / D1 (both stride halfN)
// MODE 2: col<64 -> C0 f32 stride XDS (xdbl); col>=64 -> softplus(acc+b_dt[d])
//         stored bf16 to D0 at d=col-64, stride DI (delta)
// ---------------------------------------------------------------------------
template<int MODE>
__global__ __launch_bounds__(256) void gemm_bf16_mfma(
    const unsigned short* __restrict__ A, const unsigned short* __restrict__ BT,
    float* __restrict__ C0, unsigned short* __restrict__ D0,
    unsigned short* __restrict__ D1, const float* __restrict__ b_dt,
    int M, int N, int K, int halfN)
{
    __shared__ __align__(16) char lds[64 * 80 * 2];
    char* As = lds;
    char* Bs = lds + 64 * 80;
    const int tid = threadIdx.x;
    const int w = tid >> 6, lane = tid & 63;
    const int wm = w >> 1, wn = w & 1;
    const int row0 = blockIdx.x * 64, col0 = blockIdx.y * 64;
    const int r = tid >> 2, cch = tid & 3;
    const int l15 = lane & 15, k8 = lane >> 4;

    f32x4 acc[2][2] = {};
    for (int k0 = 0; k0 < K; k0 += 32) {
        *(float4*)(As + r * 80 + cch * 16) =
            *(const float4*)(A + (size_t)(row0 + r) * K + k0 + cch * 8);
        *(float4*)(Bs + r * 80 + cch * 16) =
            *(const float4*)(BT + (size_t)(col0 + r) * K + k0 + cch * 8);
        __syncthreads();
        bf16x8 a0 = *(const bf16x8*)(As + (wm * 32 +      l15) * 80 + k8 * 16);
        bf16x8 a1 = *(const bf16x8*)(As + (wm * 32 + 16 + l15) * 80 + k8 * 16);
        bf16x8 b0 = *(const bf16x8*)(Bs + (wn * 32 +      l15) * 80 + k8 * 16);
        bf16x8 b1 = *(const bf16x8*)(Bs + (wn * 32 + 16 + l15) * 80 + k8 * 16);
        acc[0][0] = __builtin_amdgcn_mfma_f32_16x16x32_bf16(a0, b0, acc[0][0], 0, 0, 0);
        acc[0][1] = __builtin_amdgcn_mfma_f32_16x16x32_bf16(a0, b1, acc[0][1], 0, 0, 0);
        acc[1][0] = __builtin_amdgcn_mfma_f32_16x16x32_bf16(a1, b0, acc[1][0], 0, 0, 0);
        acc[1][1] = __builtin_amdgcn_mfma_f32_16x16x32_bf16(a1, b1, acc[1][1], 0, 0, 0);
        __syncthreads();
    }

    #pragma unroll
    for (int fm = 0; fm < 2; ++fm)
        #pragma unroll
        for (int fn = 0; fn < 2; ++fn)
            #pragma unroll
            for (int reg = 0; reg < 4; ++reg) {
                const int row = row0 + wm * 32 + fm * 16 + k8 * 4 + reg;
                const int col = col0 + wn * 32 + fn * 16 + l15;
                const float v = acc[fm][fn][reg];
                if (MODE == 0) {
                    C0[(size_t)row * N + col] = v;
                } else if (MODE == 1) {
                    if (col < halfN) D0[(size_t)row * halfN + col] = f2bf(v);
                    else             D1[(size_t)row * halfN + col - halfN] = f2bf(v);
                } else {
                    if (col < 64) {
                        C0[(size_t)row * XDS + col] = v;
                    } else {
                        const int d = col - 64;
                        const float t = v + b_dt[d];
                        const float dl = (t > 20.f) ? t
                            : LN2 * __log2f(1.f + fexp2(t * LOG2E));
                        D0[(size_t)row * DI + d] = f2bf(dl);
                    }
                }
            }
}

// ---------------------------------------------------------------------------
// Depthwise 3x3 conv (channel-last, bf16 in), bias + SiLU.
// xi_bf (B,H,W,DI bf16) -> u_bf written into Across cols 0..383 (stride KA)
// ---------------------------------------------------------------------------
__global__ __launch_bounds__(256) void conv_dw_silu(
    const unsigned short* __restrict__ xi_bf, const float* __restrict__ conv_w,
    const float* __restrict__ conv_b, unsigned short* __restrict__ Across)
{
    int idx = blockIdx.x * 256 + threadIdx.x;   // total BB*HH*WW*96
    int c4 = idx % 96;
    int rest = idx / 96;
    int w = rest % WW; rest /= WW;
    int h = rest % HH;
    int b = rest / HH;
    int c = c4 * 4;

    float wgt[4][9];
    #pragma unroll
    for (int q = 0; q < 4; ++q)
        #pragma unroll
        for (int t = 0; t < 9; ++t)
            wgt[q][t] = conv_w[(c + q) * 9 + t];

    float4 acc = *(const float4*)&conv_b[c];
    #pragma unroll
    for (int kh = 0; kh < 3; ++kh) {
        int hh = h + kh - 1;
        if ((unsigned)hh >= HH) continue;
        #pragma unroll
        for (int kw = 0; kw < 3; ++kw) {
            int ww = w + kw - 1;
            if ((unsigned)ww >= WW) continue;
            const ushort4 xv = *(const ushort4*)
                &xi_bf[(((size_t)(b * HH + hh)) * WW + ww) * DI + c];
            int t = kh * 3 + kw;
            acc.x += bf2f(xv.x) * wgt[0][t];
            acc.y += bf2f(xv.y) * wgt[1][t];
            acc.z += bf2f(xv.z) * wgt[2][t];
            acc.w += bf2f(xv.w) * wgt[3][t];
        }
    }
    acc.x = fsilu(acc.x); acc.y = fsilu(acc.y);
    acc.z = fsilu(acc.z); acc.w = fsilu(acc.w);
    size_t off = (((size_t)b * LL) + h * WW + w) * KA + c;
    *(ushort4*)&Across[off] = make_ushort4(f2bf(acc.x), f2bf(acc.y), f2bf(acc.z), f2bf(acc.w));
}

// ---------------------------------------------------------------------------
// Scan phase 1 v8: thread per (b,chunk,d); delta precomputed (bf16,
// coalesced); u bf16 coalesced; Bs via uniform global reads with 1-deep
// rolling prefetch (R8 measured-best shape).  Writes AH {ap, h} pairs.
// ---------------------------------------------------------------------------
__global__ __launch_bounds__(384) void scan_p1_v8(
    const unsigned short* __restrict__ uA, const unsigned short* __restrict__ delta_bf,
    const float* __restrict__ xdbl, const float* __restrict__ A_log,
    float* __restrict__ AH)
{
    const int d = threadIdx.x;
    const int bc = blockIdx.x;                        // b*NC + c
    const int b = bc / NC, c = bc % NC;
    const size_t rbase = (size_t)(b * LL + c * CH);

    float Adn[NS], h[NS];
    {
        const float4* ap4 = (const float4*)(A_log + d * NS);
        #pragma unroll
        for (int q = 0; q < 4; ++q) {
            const float4 v = ap4[q];
            Adn[q*4+0] = -__expf(v.x) * LOG2E;
            Adn[q*4+1] = -__expf(v.y) * LOG2E;
            Adn[q*4+2] = -__expf(v.z) * LOG2E;
            Adn[q*4+3] = -__expf(v.w) * LOG2E;
        }
    }
    #pragma unroll
    for (int n = 0; n < NS; ++n) h[n] = 0.f;

    const unsigned short* up = uA + rbase * KA + d;
    const unsigned short* dp = delta_bf + rbase * DI + d;
    const float* xp = xdbl + rbase * XDS;

    float uu = bf2f(up[0]), dlt = bf2f(dp[0]);
    float4 bb0 = *(const float4*)(xp + 12), bb1 = *(const float4*)(xp + 16);
    float4 bb2 = *(const float4*)(xp + 20), bb3 = *(const float4*)(xp + 24);
    float sdlt = 0.f;

    #pragma unroll
    for (int i = 0; i < CH; ++i) {
        // prefetch step i+1 (OOB-by-one on last iter: padded rows)
        const float uu_n  = bf2f(up[(size_t)(i + 1) * KA]);
        const float dlt_n = bf2f(dp[(size_t)(i + 1) * DI]);
        const float* xn = xp + (size_t)(i + 1) * XDS;
        const float4 bn0 = *(const float4*)(xn + 12), bn1 = *(const float4*)(xn + 16);
        const float4 bn2 = *(const float4*)(xn + 20), bn3 = *(const float4*)(xn + 24);

        const float du = dlt * uu;
        sdlt += dlt;
        const float bs[NS] = {bb0.x, bb0.y, bb0.z, bb0.w, bb1.x, bb1.y, bb1.z, bb1.w,
                              bb2.x, bb2.y, bb2.z, bb2.w, bb3.x, bb3.y, bb3.z, bb3.w};
        #pragma unroll
        for (int n = 0; n < NS; ++n) {
            const float a = fexp2(dlt * Adn[n]);
            h[n] = a * h[n] + du * bs[n];
        }
        uu = uu_n; dlt = dlt_n;
        bb0 = bn0; bb1 = bn1; bb2 = bn2; bb3 = bn3;
    }
    float* dst = AH + 2 * (((size_t)bc * DI + d) * NS);
    #pragma unroll
    for (int q = 0; q < 8; ++q) {
        const float ap0 = fexp2(sdlt * Adn[2*q]);
        const float ap1 = fexp2(sdlt * Adn[2*q+1]);
        *(float4*)(dst + 4 * q) = make_float4(ap0, h[2*q], ap1, h[2*q+1]);
    }
}

// ---------------------------------------------------------------------------
// Scan phase 2 v2: sequential over NC chunks per (b,d,n) chain, 4-deep
// prefetch on interleaved float2 AH.  Writes chunk-entry state to compact Hinc.
// ---------------------------------------------------------------------------
__global__ __launch_bounds__(256) void scan_p2_v2(
    const float2* __restrict__ AH, float* __restrict__ Hinc)
{
    const int gid = blockIdx.x * 256 + threadIdx.x;   // (b*DI + d)*NS + n
    const int dn = gid % (DI * NS);
    const int b  = gid / (DI * NS);
    const size_t base = (size_t)b * NC * DI * NS + dn;
    const size_t cs = (size_t)DI * NS;

    float2 buf[4];
    #pragma unroll
    for (int k = 0; k < 4; ++k) buf[k] = AH[base + (size_t)k * cs];

    float hin = 0.f;
    for (int c = 0; c < NC; c += 4) {
        #pragma unroll
        for (int k = 0; k < 4; ++k) {
            const int cn = (c + k + 4 < NC) ? (c + k + 4) : (NC - 1);  // clamp
            const float2 nxt = AH[base + (size_t)cn * cs];
            const float2 cur = buf[k];
            Hinc[base + (size_t)(c + k) * cs] = hin;
            hin = cur.x * hin + cur.y;
            buf[k] = nxt;
        }
    }
}

// ---------------------------------------------------------------------------
// Scan phase 3 + LayerNorm + SiLU(z) gate, v6: R8 measured-best rolling
// shape (global uniform Bs/Cs, no LDS staging) + precomputed delta (bf16,
// coalesced) + compact Hinc + bf16 u/z.  Parity-barrier LN per step.
// ---------------------------------------------------------------------------
__global__ __launch_bounds__(384) void scan_p3_ln_v6(
    const unsigned short* __restrict__ uA, const unsigned short* __restrict__ z_bf,
    const unsigned short* __restrict__ delta_bf, const float* __restrict__ xdbl,
    const float* __restrict__ Hinc, const float* __restrict__ A_log,
    const float* __restrict__ Dvec, const float* __restrict__ ln_g,
    const float* __restrict__ ln_b, unsigned short* __restrict__ yin_bf)
{
    __shared__ float red_s[2][8], red_sq[2][8];
    const int d = threadIdx.x;
    const int bc = blockIdx.x;                        // b*NC + c
    const int b = bc / NC, c = bc % NC;
    const int wid = d >> 6, lane = d & 63;
    const size_t rbase = (size_t)(b * LL + c * CH);

    float Adn[NS], h[NS];
    {
        const float4* ap4 = (const float4*)(A_log + d * NS);
        #pragma unroll
        for (int q = 0; q < 4; ++q) {
            const float4 v = ap4[q];
            Adn[q*4+0] = -__expf(v.x) * LOG2E;
            Adn[q*4+1] = -__expf(v.y) * LOG2E;
            Adn[q*4+2] = -__expf(v.z) * LOG2E;
            Adn[q*4+3] = -__expf(v.w) * LOG2E;
        }
    }
    {
        const float* hp = Hinc + ((size_t)bc * DI + d) * NS;
        #pragma unroll
        for (int q = 0; q < 4; ++q) {
            const float4 v = *(const float4*)(hp + 4 * q);
            h[q*4] = v.x; h[q*4+1] = v.y; h[q*4+2] = v.z; h[q*4+3] = v.w;
        }
    }
    const float Dd = Dvec[d];
    const float lg = ln_g[d], lb = ln_b[d];

    const unsigned short* up = uA + rbase * KA + d;
    const unsigned short* zp = z_bf + rbase * DI + d;
    const unsigned short* dp = delta_bf + rbase * DI + d;
    const float* xp = xdbl + rbase * XDS;
    unsigned short* yp = yin_bf + rbase * DI + d;

    float uu = bf2f(up[0]), zz = bf2f(zp[0]), dlt = bf2f(dp[0]);
    float4 bb0 = *(const float4*)(xp + 12), bb1 = *(const float4*)(xp + 16);
    float4 bb2 = *(const float4*)(xp + 20), bb3 = *(const float4*)(xp + 24);
    float4 cc0 = *(const float4*)(xp + 28), cc1 = *(const float4*)(xp + 32);
    float4 cc2 = *(const float4*)(xp + 36), cc3 = *(const float4*)(xp + 40);

    #pragma unroll
    for (int i = 0; i < CH; ++i) {
        // prefetch step i+1 (OOB-by-one on last iter: padded rows)
        const float uu_n  = bf2f(up[(size_t)(i + 1) * KA]);
        const float zz_n  = bf2f(zp[(size_t)(i + 1) * DI]);
        const float dlt_n = bf2f(dp[(size_t)(i + 1) * DI]);
        const float* xn = xp + (size_t)(i + 1) * XDS;
        const float4 bn0 = *(const float4*)(xn + 12), bn1 = *(const float4*)(xn + 16);
        const float4 bn2 = *(const float4*)(xn + 20), bn3 = *(const float4*)(xn + 24);
        const float4 cn0 = *(const float4*)(xn + 28), cn1 = *(const float4*)(xn + 32);
        const float4 cn2 = *(const float4*)(xn + 36), cn3 = *(const float4*)(xn + 40);

        const float du = dlt * uu;
        const float bs[NS] = {bb0.x, bb0.y, bb0.z, bb0.w, bb1.x, bb1.y, bb1.z, bb1.w,
                              bb2.x, bb2.y, bb2.z, bb2.w, bb3.x, bb3.y, bb3.z, bb3.w};
        const float cs[NS] = {cc0.x, cc0.y, cc0.z, cc0.w, cc1.x, cc1.y, cc1.z, cc1.w,
                              cc2.x, cc2.y, cc2.z, cc2.w, cc3.x, cc3.y, cc3.z, cc3.w};
        float acc = uu * Dd;
        #pragma unroll
        for (int n = 0; n < NS; ++n) {
            const float a = fexp2(dlt * Adn[n]);
            h[n] = a * h[n] + du * bs[n];
            acc += h[n] * cs[n];
        }
        // block LayerNorm reduce over 384 d's (parity LDS double-buffer)
        float s = acc, sq = acc * acc;
        #pragma unroll
        for (int m = 1; m < 64; m <<= 1) {
            s  += __shfl_xor(s, m);
            sq += __shfl_xor(sq, m);
        }
        const int par = i & 1;
        if (lane == 0) { red_s[par][wid] = s; red_sq[par][wid] = sq; }
        __syncthreads();
        s = red_s[par][0] + red_s[par][1] + red_s[par][2]
          + red_s[par][3] + red_s[par][4] + red_s[par][5];
        sq = red_sq[par][0] + red_sq[par][1] + red_sq[par][2]
           + red_sq[par][3] + red_sq[par][4] + red_sq[par][5];
        const float mu = s * (1.f / DI);
        const float var = sq * (1.f / DI) - mu * mu;
        const float inv = rsqrtf(var + 1e-5f);
        const float yn = (acc - mu) * inv * lg + lb;
        yp[(size_t)i * DI] = f2bf(yn * fsilu(zz));

        uu = uu_n; zz = zz_n; dlt = dlt_n;
        bb0 = bn0; bb1 = bn1; bb2 = bn2; bb3 = bn3;
        cc0 = cn0; cc1 = cn1; cc2 = cn2; cc3 = cn3;
    }
}

// ---------------------------------------------------------------------------
extern "C" void kernel_launch(void* const* d_in, const int* in_sizes, int n_in,
                              void* d_out, int out_size, void* d_ws, size_t ws_size,
                              hipStream_t stream)
{
    const float* x      = (const float*)d_in[0];
    const float* prompt = (const float*)d_in[1];
    const float* W_in   = (const float*)d_in[2];
    const float* conv_w = (const float*)d_in[3];
    const float* conv_b = (const float*)d_in[4];
    const float* Wx     = (const float*)d_in[5];
    const float* Wdt    = (const float*)d_in[6];
    const float* b_dt   = (const float*)d_in[7];
    const float* A_log  = (const float*)d_in[8];
    const float* Dvec   = (const float*)d_in[9];
    const float* Wp     = (const float*)d_in[10];
    const float* ln_g   = (const float*)d_in[11];
    const float* ln_b   = (const float*)d_in[12];
    const float* Wout   = (const float*)d_in[13];
    float* out = (float*)d_out;

    char* p = (char*)d_ws;
    unsigned short* xi_bf   = (unsigned short*)p; p += (size_t)ROWS * DI * 2;        // 12.6 MB
    unsigned short* z_bf    = (unsigned short*)p; p += (size_t)(ROWS + 1) * DI * 2;  // 12.6 MB
    unsigned short* Across  = (unsigned short*)p; p += (size_t)(ROWS + 1) * KA * 2;  // 18.9 MB
    float*          xdbl    = (float*)p;          p += (size_t)(ROWS + 1) * XDS * 4; // 4.2 MB
    unsigned short* delta_bf= (unsigned short*)p; p += (size_t)(ROWS + 1) * DI * 2;  // 12.6 MB
    char* ahreg = p;
    float* AH   = (float*)p;               p += (size_t)BB * NC * DI * NS * 8;       // 50.3 MB
    float* Hinc = (float*)p;               p += (size_t)BB * NC * DI * NS * 4;       // 25.2 MB
    unsigned short* WinT  = (unsigned short*)p;  p += (size_t)(2 * DI) * DM * 2;     // 288 KB
    unsigned short* BxTE  = (unsigned short*)p;  p += (size_t)NXE * KA * 2;          // 516 KB
    unsigned short* WoutT = (unsigned short*)p;  p += (size_t)DM * DI * 2;           // 144 KB
    // x_bf lives inside AH region (dead after gemm1, before scan_p1 writes AH)
    unsigned short* x_bf = (unsigned short*)ahreg;                                   // 6.3 MB
    unsigned short* yin_bf = xi_bf;  // xi dead after conv

    // 0. conversions / weight builds (independent)
    f32_to_bf16_vec<<<(ROWS * DM / 4 + 255) / 256, 256, 0, stream>>>(x, x_bf, ROWS * DM / 4);
    prompt_to_across<<<(ROWS * (DM / 4) + 255) / 256, 256, 0, stream>>>(prompt, Across);
    build_bt<<<(2 * DI * DM + 255) / 256, 256, 0, stream>>>(W_in, WinT, DM, 2 * DI, 2 * DI);
    build_bxt_ext<<<(NXE * KA + 255) / 256, 256, 0, stream>>>(Wx, Wp, Wdt, BxTE);
    build_bt<<<(DM * DI + 255) / 256, 256, 0, stream>>>(Wout, WoutT, DI, DM, DM);

    // 1. xz = x @ W_in -> xi_bf | z_bf (both bf16)   (M=16384, N=768, K=192)
    {
        dim3 g(ROWS / 64, (2 * DI) / 64);
        gemm_bf16_mfma<1><<<g, 256, 0, stream>>>(x_bf, WinT, nullptr, xi_bf, z_bf,
                                                 nullptr, ROWS, 2 * DI, DM, DI);
    }
    // 2. depthwise conv + bias + SiLU -> u_bf into Across cols 0..383
    conv_dw_silu<<<(BB * HH * WW * 96) / 256, 256, 0, stream>>>(xi_bf, conv_w, conv_b, Across);
    // 3. [xdbl | delta] = [u | prompt] @ B'ext  (M=16384, N=448, K=576)
    //    cols 0..63 -> xdbl f32; cols 64..447 -> softplus(+b_dt) -> delta bf16
    {
        dim3 g(ROWS / 64, NXE / 64);
        gemm_bf16_mfma<2><<<g, 256, 0, stream>>>(Across, BxTE, xdbl, delta_bf,
                                                 nullptr, b_dt, ROWS, NXE, KA, 64);
    }
    // 4-6. chunked selective scan (p2 writes compact Hinc)
    scan_p1_v8<<<BB * NC, 384, 0, stream>>>(Across, delta_bf, xdbl, A_log, AH);
    scan_p2_v2<<<(BB * DI * NS) / 256, 256, 0, stream>>>((const float2*)AH, Hinc);
    // 7. scan replay + LayerNorm + SiLU(z) gate -> yin_bf (reuses xi_bf)
    scan_p3_ln_v6<<<BB * NC, 384, 0, stream>>>(Across, z_bf, delta_bf, xdbl, Hinc,
                                               A_log, Dvec, ln_g, ln_b, yin_bf);
    // 8. out = yin @ Wout  (M=16384, N=192, K=384)
    {
        dim3 g(ROWS / 64, DM / 64);
        gemm_bf16_mfma<0><<<g, 256, 0, stream>>>(yin_bf, WoutT, out, nullptr, nullptr,
                                                 nullptr, ROWS, DM, DI, 0);
    }
}